// Round 8
// baseline (874.999 us; speedup 1.0000x reference)
//
#include <hip/hip_runtime.h>

#define BATCH 256
#define SEQ   250
#define HID   512
#define INDIM 5

#define NBLK  256
#define NCH   16   // independent batch chains
#define MB    16   // batch rows per chain/block
#define HB    32   // hidden cols per block (member)
#define NMEM  16   // members per chain (HID/HB)

// member-major h buffers: slot (2) | chain bt (16) | member j (16) | 1KB
// LDS member block: 16 rows x 36 ushorts (72B: 64B data + 8B pad)
#define LROWU 36          // ushorts per LDS row
#define LMEMU 576         // ushorts per member block (16*36)
#define SLOT_BYTES (BATCH * HID * 2)   // 256KB per slot

typedef __attribute__((ext_vector_type(8))) short short8;
typedef __attribute__((ext_vector_type(4))) float f32x4;
typedef __attribute__((ext_vector_type(4))) unsigned int u32x4;

__device__ __forceinline__ float sigmoidf_fast(float x) {
  return 1.0f / (1.0f + __expf(-x));
}
__device__ __forceinline__ float tanhf_fast(float x) {
  return 2.0f / (1.0f + __expf(-2.0f * x)) - 1.0f;
}
__device__ __forceinline__ unsigned short f2bf_rne(float x) {
  union { float f; unsigned u; } v; v.f = x;
  unsigned r = v.u + 0x7fffu + ((v.u >> 16) & 1u);
  return (unsigned short)(r >> 16);
}
__device__ __forceinline__ float bf2f(unsigned short h) {
  union { unsigned u; float f; } v; v.u = ((unsigned)h) << 16;
  return v.f;
}

// R22 = R21 (remap + hybrid poll, verified 665us) + detect-path latency
// cuts, protocol unchanged:
//  (a) EARLY PROBE: during publish (before the h-store), lanes<16 issue
//      the L2 probe of their input flag for the NEXT step; the publish
//      drain vmcnt(0) completes it for free. Next poll often reduces to
//      a register compare (zero round trips).
//  (b) PING-PONG MISS LOOP: two probes in flight, vmcnt(1) waits ->
//      ~150cy check period (was ~300). Every 8th iteration = R21 fused
//      dual-probe (L2+MALL) backstop -> cannot hang. Exit drains
//      vmcnt(0) so no in-flight probe can clobber a reused VGPR.
__global__ __launch_bounds__(256, 1) void lstm_persist(
    const float* __restrict__ strokes, const float* __restrict__ W_ih,
    const float* __restrict__ W_hh, const float* __restrict__ b_ih,
    const float* __restrict__ b_hh, const float* __restrict__ W_out,
    const float* __restrict__ b_out, float* __restrict__ out,
    unsigned short* __restrict__ hbuf,   // 2 slots * 256KB, member-major
    int* __restrict__ flagsML,           // 16*16*16 ints, MALL copy (poison<0)
    int* __restrict__ flagsL2,           // 16*16*16 ints, L2 copy   (poison<0)
    int* __restrict__ xcd_ids,           // 256 ints (poison < 0)
    int* __restrict__ vflag)             // 16*16 ints (unused)
{
  const int tid  = threadIdx.x;
  const int bid  = blockIdx.x;
  const int wv   = tid >> 6;     // wave id = col-stripe 0..3 (8 cols each)
  const int lane = tid & 63;
  const int n16  = lane & 15;
  const int q    = lane >> 4;
  const int j7   = n16 & 7;
  const int hi   = n16 >> 3;     // 0: holds gates i,g ; 1: holds gates f,o

  __shared__ unsigned short h_lds[NMEM * LMEMU];  // 18KB member-major h tile
  __shared__ int xid_lds[NBLK];                   // 1KB gathered XCC ids

  // ---- publish my XCC id (device scope)
  unsigned xcc;
  asm volatile("s_getreg_b32 %0, hwreg(HW_REG_XCC_ID)" : "=s"(xcc));
  xcc &= 0xfu;
  if (tid == 0) {
    __hip_atomic_store(&xcd_ids[bid], (int)xcc, __ATOMIC_RELAXED,
                       __HIP_MEMORY_SCOPE_AGENT);
  }
  // ---- gather ALL 256 ids (thread tid spins on block tid's id).
  {
    const int* xp = &xcd_ids[tid];
    int v;
    do {
      v = __hip_atomic_load(xp, __ATOMIC_RELAXED, __HIP_MEMORY_SCOPE_AGENT);
    } while (v < 0);
    xid_lds[tid] = v & 15;
  }
  __syncthreads();

  // ---- role decision (per-thread, uniform inputs -> uniform outputs).
  unsigned long long pack = 0;
  bool bad = false;
  int myrank = 0;
  for (int b = 0; b < NBLK; ++b) {
    const int x = xid_lds[b];
    if (x < 8) pack += 1ull << (x * 8); else bad = true;
    if (b < bid && x == (int)xcc) ++myrank;
  }
  const bool remap = !bad && (pack == 0x2020202020202020ull);
  int bt, ht, fastI;
  if (remap) {
    bt = (int)xcc * 2 + (myrank >> 4);   // chain: 2 per XCD
    ht = myrank & 15;                    // member within chain
    fastI = 1;                           // same-XCD guaranteed
  } else {
    bt = bid & 15;                       // identity roles (R18)
    ht = bid >> 4;
    bool same = true;
    #pragma unroll
    for (int m = 0; m < 16; ++m)
      same = same && (xid_lds[bt + 16 * m] == (int)xcc);
    fastI = same ? 1 : 0;
  }
  const bool fast = fastI != 0;

  const int mycol = ht * HB + wv * 8 + j7;   // global hidden col

  // ---- per-thread W_ih slice + combined bias, all 4 gates of my col
  float wih[4][INDIM], bias[4];
  #pragma unroll
  for (int g = 0; g < 4; ++g) {
    const int r = g * HID + mycol;
    #pragma unroll
    for (int i = 0; i < INDIM; ++i) wih[g][i] = W_ih[r * INDIM + i];
    bias[g] = b_ih[r] + b_hh[r];
  }

  // ---- W_hh bf16 MFMA B-fragments, wave-local gate mapping:
  //   N-slot s = nt*16+n16 -> W_hh row (s>>3)*HID + ht*32 + wv*8 + (s&7)
  //   K-block kb rotated: wfrag[i][nt] <-> kb=(wv*4+i)&15
  short8 wfrag[16][2];
  {
    #pragma unroll
    for (int i = 0; i < 16; ++i) {
      const int kb = (wv * 4 + i) & 15;
      #pragma unroll
      for (int nt = 0; nt < 2; ++nt) {
        const int s = nt * 16 + n16;
        const int row = (s >> 3) * HID + ht * HB + wv * 8 + (s & 7);
        const float* p = W_hh + (size_t)row * HID + kb * 32 + q * 8;
        short8 f;
        #pragma unroll
        for (int j = 0; j < 8; ++j) f[j] = (short)f2bf_rne(p[j]);
        wfrag[i][nt] = f;
      }
    }
  }
  __syncthreads();

  // this thread's two batch rows (within chain): row0, row0+1
  const int row0 = q * 4 + 2 * hi;
  const float* sp0 = strokes + (size_t)(bt * MB + row0) * SEQ * INDIM;
  const float* sp1 = sp0 + (size_t)SEQ * INDIM;

  const int j0m = wv * 4;             // this wave's first member (staging)

  // loop-invariant poll addresses (lanes 0..15: one input flag each)
  const int fi_poll = (bt * 16 + (j0m + (lane >> 2))) * 16 + (lane & 3) * 4;
  const int* fpL = &flagsL2[fi_poll];
  const int* fpM = &flagsML[fi_poll];
  int ev = 0;                         // early-probe carried value

  float c0 = 0.f, c1 = 0.f;

  for (int t = 0; t < SEQ; ++t) {
    unsigned short* hprev = hbuf + (((t & 1) ^ 1) ? (SLOT_BYTES / 2) : 0);
    unsigned short* hcur  = hbuf + ((t & 1) ? (SLOT_BYTES / 2) : 0);

    // strokes for this step (2 rows) - issued early, drained by poll/stage
    float sA[INDIM], sB[INDIM];
    #pragma unroll
    for (int i = 0; i < INDIM; ++i) {
      sA[i] = sp0[t * INDIM + i];
      sB[i] = sp1[t * INDIM + i];
    }

    f32x4 acc[2][2] = {};   // [ntile][parity]
    if (t > 0) {
      // ---- poll: early-probe check first (zero round trips on hit),
      // else ping-pong pipelined L2 probes + periodic dual backstop.
      if (lane < 16) {
        if (fast) {
          if (ev < t) {
            int vA, vB;
            asm volatile("global_load_dword %0, %1, off sc0"
                         : "=v"(vA) : "v"(fpL) : "memory");
            int it = 0;
            for (;;) {
              asm volatile("global_load_dword %0, %1, off sc0\n\t"
                           "s_waitcnt vmcnt(1)"
                           : "=v"(vB) : "v"(fpL) : "memory");
              if (vA >= t) break;
              if ((++it & 7) == 0) {
                // MALL backstop (drains everything) -> cannot hang
                int m1, m2;
                asm volatile("global_load_dword %0, %2, off sc0\n\t"
                             "global_load_dword %1, %3, off sc0 sc1\n\t"
                             "s_waitcnt vmcnt(0)"
                             : "=v"(m1), "=v"(m2)
                             : "v"(fpL), "v"(fpM) : "memory");
                if ((m1 > m2 ? m1 : m2) >= t) break;
                asm volatile("global_load_dword %0, %1, off sc0"
                             : "=v"(vA) : "v"(fpL) : "memory");
                continue;
              }
              asm volatile("global_load_dword %0, %1, off sc0\n\t"
                           "s_waitcnt vmcnt(1)"
                           : "=v"(vA) : "v"(fpL) : "memory");
              if (vB >= t) break;
            }
            // drain in-flight probe: its dest VGPR may be reused below
            asm volatile("s_waitcnt vmcnt(0)" ::: "memory");
          }
        } else {
          while (__hip_atomic_load(fpM, __ATOMIC_RELAXED,
                                   __HIP_MEMORY_SCOPE_AGENT) < t) { }
        }
      }
      // ---- stage this wave's 4 members (4 x 1KB) into LDS
      const char* base = reinterpret_cast<const char*>(hprev) + bt * 16384
                       + j0m * 1024;
      u32x4 tmp[4];
      if (fast) {
        #pragma unroll
        for (int i = 0; i < 4; ++i)
          asm volatile("global_load_dwordx4 %0, %1, off sc0"
                       : "=v"(tmp[i])
                       : "v"(base + (size_t)(i * 64 + lane) * 16) : "memory");
      } else {
        #pragma unroll
        for (int i = 0; i < 4; ++i)
          asm volatile("global_load_dwordx4 %0, %1, off sc0 sc1"
                       : "=v"(tmp[i])
                       : "v"(base + (size_t)(i * 64 + lane) * 16) : "memory");
      }
      asm volatile("s_waitcnt vmcnt(0)" ::: "memory");
      #pragma unroll
      for (int i = 0; i < 4; ++i) {
        const int idx = i * 64 + lane;     // 16B chunk index in wave's 4KB
        const int m   = j0m + (idx >> 6);  // member (64 chunks each)
        const int c   = idx & 63;          // chunk in member
        *reinterpret_cast<u32x4*>(
            &h_lds[m * LMEMU + (c >> 2) * LROWU + (c & 3) * 8]) = tmp[i];
      }

      // ---- early MFMA: the 4 kb (== members) this wave itself staged
      #pragma unroll
      for (int i = 0; i < 4; ++i) {
        const int kb = wv * 4 + i;         // own member, <16
        const short8 a = *reinterpret_cast<const short8*>(
            &h_lds[kb * LMEMU + n16 * LROWU + q * 8]);
        #pragma unroll
        for (int nt = 0; nt < 2; ++nt)
          acc[nt][i & 1] = __builtin_amdgcn_mfma_f32_16x16x32_bf16(
              a, wfrag[i][nt], acc[nt][i & 1], 0, 0, 0);
      }
      __syncthreads();   // sync#1 (the ONLY per-step barrier)
      #pragma unroll
      for (int i = 4; i < 16; ++i) {
        const int kb = (wv * 4 + i) & 15;
        const short8 a = *reinterpret_cast<const short8*>(
            &h_lds[kb * LMEMU + n16 * LROWU + q * 8]);
        #pragma unroll
        for (int nt = 0; nt < 2; ++nt)
          acc[nt][i & 1] = __builtin_amdgcn_mfma_f32_16x16x32_bf16(
              a, wfrag[i][nt], acc[nt][i & 1], 0, 0, 0);
      }
    }

    // ---- wave-local activation. C-layout: col=slot n16, row=q*4+r.
    // Lane (hi=0) holds gates {i,g}, partner lane^8 holds {f,o};
    // exchange per cell row via shfl_xor(8). No LDS, no barrier.
    const f32x4 S0 = acc[0][0] + acc[0][1];   // slot nt=0 -> gate hi
    const f32x4 S1 = acc[1][0] + acc[1][1];   // slot nt=1 -> gate hi+2
    float hv0 = 0.f, hv1 = 0.f;
    #pragma unroll
    for (int e = 0; e < 2; ++e) {
      float mine0 = hi ? S0[2 + e] : S0[e];
      float send0 = hi ? S0[e]     : S0[2 + e];
      float mine1 = hi ? S1[2 + e] : S1[e];
      float send1 = hi ? S1[e]     : S1[2 + e];
      float got0 = __shfl_xor(send0, 8);
      float got1 = __shfl_xor(send1, 8);
      float pi = hi ? got0  : mine0;
      float pf = hi ? mine0 : got0;
      float pg = hi ? got1  : mine1;
      float po = hi ? mine1 : got1;
      const float* s = e ? sB : sA;
      pi += bias[0] + s[0]*wih[0][0] + s[1]*wih[0][1] + s[2]*wih[0][2]
                    + s[3]*wih[0][3] + s[4]*wih[0][4];
      pf += bias[1] + s[0]*wih[1][0] + s[1]*wih[1][1] + s[2]*wih[1][2]
                    + s[3]*wih[1][3] + s[4]*wih[1][4];
      pg += bias[2] + s[0]*wih[2][0] + s[1]*wih[2][1] + s[2]*wih[2][2]
                    + s[3]*wih[2][3] + s[4]*wih[2][4];
      po += bias[3] + s[0]*wih[3][0] + s[1]*wih[3][1] + s[2]*wih[3][2]
                    + s[3]*wih[3][3] + s[4]*wih[3][4];
      float ig = sigmoidf_fast(pi);
      float fg = sigmoidf_fast(pf);
      float gg = tanhf_fast(pg);
      float og = sigmoidf_fast(po);
      float& c = e ? c1 : c0;
      c = fg * c + ig * gg;
      float hv = og * tanhf_fast(c);
      if (e == 0) hv0 = hv; else hv1 = hv;
    }

    // ---- EARLY PROBE for next step's poll: issued before the h-store;
    // the publish drain below completes it (no extra latency).
    if (fast && lane < 16) {
      asm volatile("global_load_dword %0, %1, off sc0"
                   : "=v"(ev) : "v"(fpL) : "memory");
    }

    // ---- pack 2 adjacent cols into one dword via shfl_xor(1):
    // even j7 stores row row0 (cols j7,j7+1); odd j7 stores row row0+1.
    {
      float sendh = (j7 & 1) ? hv0 : hv1;
      float rh = __shfl_xor(sendh, 1);
      unsigned lo = (j7 & 1) ? (unsigned)f2bf_rne(rh)  : (unsigned)f2bf_rne(hv0);
      unsigned hh = (j7 & 1) ? (unsigned)f2bf_rne(hv1) : (unsigned)f2bf_rne(rh);
      unsigned pack2 = lo | (hh << 16);
      const int srow = row0 + (j7 & 1);
      const int colp = wv * 8 + (j7 & ~1);
      unsigned* hp = reinterpret_cast<unsigned*>(
          reinterpret_cast<char*>(hcur) + bt * 16384 + ht * 1024
          + srow * 64 + colp * 2);
      if (fast) {
        asm volatile("global_store_dword %0, %1, off sc0"
                     :: "v"(hp), "v"(pack2) : "memory");
      } else {
        __hip_atomic_store(hp, pack2, __ATOMIC_RELAXED,
                           __HIP_MEMORY_SCOPE_AGENT);
      }
    }

    // ---- per-wave publish: drain OWN h stores (+ early probe), then flag
    asm volatile("s_waitcnt vmcnt(0)" ::: "memory");
    const int gen = t + 1;
    if (lane == 0) {
      const int fi = (bt * 16 + ht) * 16 + wv * 4;
      if (fast) {
        asm volatile("global_store_dword %0, %1, off sc0"
                     :: "v"(&flagsL2[fi]), "v"(gen) : "memory");
      }
      __hip_atomic_store(&flagsML[fi], gen, __ATOMIC_RELAXED,
                         __HIP_MEMORY_SCOPE_AGENT);   // MALL copy
    }
  }

  // ---- final projection: member ht==0 of each chain, 16 rows
  if (ht == 0) {
    if (lane < 16) {
      if (fast) {
        int v = ev;   // early probe from last publish may already satisfy
        int it = 0;
        while (v < SEQ) {
          int v1, v2;
          if ((it & 3) == 3) {
            asm volatile("global_load_dword %0, %2, off sc0\n\t"
                         "global_load_dword %1, %3, off sc0 sc1\n\t"
                         "s_waitcnt vmcnt(0)"
                         : "=v"(v1), "=v"(v2)
                         : "v"(fpL), "v"(fpM)
                         : "memory");
          } else {
            asm volatile("global_load_dword %0, %1, off sc0\n\t"
                         "s_waitcnt vmcnt(0)"
                         : "=v"(v1) : "v"(fpL) : "memory");
            v2 = v1;
          }
          ++it;
          v = v1 > v2 ? v1 : v2;
        }
      } else {
        while (__hip_atomic_load(fpM, __ATOMIC_RELAXED,
                                 __HIP_MEMORY_SCOPE_AGENT) < SEQ) { }
      }
    }
    const char* base = reinterpret_cast<const char*>(hbuf)
                     + ((SEQ - 1) & 1) * SLOT_BYTES + bt * 16384 + j0m * 1024;
    u32x4 tmp[4];
    if (fast) {
      #pragma unroll
      for (int i = 0; i < 4; ++i)
        asm volatile("global_load_dwordx4 %0, %1, off sc0"
                     : "=v"(tmp[i])
                     : "v"(base + (size_t)(i * 64 + lane) * 16) : "memory");
    } else {
      #pragma unroll
      for (int i = 0; i < 4; ++i)
        asm volatile("global_load_dwordx4 %0, %1, off sc0 sc1"
                     : "=v"(tmp[i])
                     : "v"(base + (size_t)(i * 64 + lane) * 16) : "memory");
    }
    asm volatile("s_waitcnt vmcnt(0)" ::: "memory");
    #pragma unroll
    for (int i = 0; i < 4; ++i) {
      const int idx = i * 64 + lane;
      const int m   = j0m + (idx >> 6);
      const int c   = idx & 63;
      *reinterpret_cast<u32x4*>(
          &h_lds[m * LMEMU + (c >> 2) * LROWU + (c & 3) * 8]) = tmp[i];
    }
    __syncthreads();
    if (tid < MB) {
      const int b = bt * MB + tid;
      float s = 0.f;
      for (int k = 0; k < HID; ++k) {
        s += bf2f(h_lds[(k >> 5) * LMEMU + tid * LROWU + (k & 31)]) * W_out[k];
      }
      float raw = s + b_out[0];
      float lr = raw > 0.f ? raw : 0.1f * raw;
      out[b] = 1.0f / (1.0f + __expf(-lr));
    }
  }
}

extern "C" void kernel_launch(void* const* d_in, const int* in_sizes, int n_in,
                              void* d_out, int out_size, void* d_ws, size_t ws_size,
                              hipStream_t stream) {
  const float* strokes = (const float*)d_in[0];
  const float* W_ih    = (const float*)d_in[1];
  const float* W_hh    = (const float*)d_in[2];
  const float* b_ih    = (const float*)d_in[3];
  const float* b_hh    = (const float*)d_in[4];
  const float* W_out   = (const float*)d_in[5];
  const float* b_out   = (const float*)d_in[6];
  float* out = (float*)d_out;

  char* ws = (char*)d_ws;
  unsigned short* hbuf = (unsigned short*)ws;                 // 512 KB (2 slots)
  size_t off = (size_t)2 * SLOT_BYTES;
  int* flagsML = (int*)(ws + off);  off += 16384;             // 16 KB
  int* flagsL2 = (int*)(ws + off);  off += 16384;             // 16 KB
  int* xcd_ids = (int*)(ws + off);  off += 2048;              // 2 KB
  int* vflag   = (int*)(ws + off);                            // 1 KB (unused)

  lstm_persist<<<NBLK, 256, 0, stream>>>(strokes, W_ih, W_hh, b_ih, b_hh,
                                         W_out, b_out, out, hbuf,
                                         flagsML, flagsL2, xcd_ids, vflag);
}

// Round 9
// 825.798 us; speedup vs baseline: 1.0596x; 1.0596x over previous
//
#include <hip/hip_runtime.h>

#define BATCH 256
#define SEQ   250
#define HID   512
#define INDIM 5

#define NBLK  256
#define NCH   16   // independent batch chains
#define MB    16   // batch rows per chain/block
#define HB    32   // hidden cols per block (member)
#define NMEM  16   // members per chain (HID/HB)

// member-major h buffers: slot (2) | chain bt (16) | member j (16) | 1KB
// LDS member block: 16 rows x 36 ushorts (72B: 64B data + 8B pad)
#define LROWU 36          // ushorts per LDS row
#define LMEMU 576         // ushorts per member block (16*36)
#define SLOT_BYTES (BATCH * HID * 2)   // 256KB per slot

typedef __attribute__((ext_vector_type(8))) short short8;
typedef __attribute__((ext_vector_type(4))) float f32x4;
typedef __attribute__((ext_vector_type(4))) unsigned int u32x4;

__device__ __forceinline__ float sigmoidf_fast(float x) {
  return 1.0f / (1.0f + __expf(-x));
}
__device__ __forceinline__ float tanhf_fast(float x) {
  return 2.0f / (1.0f + __expf(-2.0f * x)) - 1.0f;
}
__device__ __forceinline__ unsigned short f2bf_rne(float x) {
  union { float f; unsigned u; } v; v.f = x;
  unsigned r = v.u + 0x7fffu + ((v.u >> 16) & 1u);
  return (unsigned short)(r >> 16);
}
__device__ __forceinline__ float bf2f(unsigned short h) {
  union { unsigned u; float f; } v; v.u = ((unsigned)h) << 16;
  return v.f;
}

// R23 = R21 (verified 665us: remap + hybrid poll; R22's early-probe/
// ping-pong REVERTED -- it lengthened the publish edge, -150us) + two
// publish-safe poll-side changes:
//  (1) STROKE PREFETCH: strokes(t+1) loaded at the BOTTOM of iteration t
//      (after flag publish, memory-clobber-pinned), landing during the
//      next poll. The poll's first vmcnt(0) no longer drains fresh
//      stroke loads (vmcnt retires in issue order).
//  (2) MALL backstop every 8th probe iteration (was 4th): avg probe cost
//      ~300cy instead of ~400cy; hang-safety preserved (backstop recurs).
// Publish path, staging, MFMA, activation, final projection: identical
// to R21.
__global__ __launch_bounds__(256, 1) void lstm_persist(
    const float* __restrict__ strokes, const float* __restrict__ W_ih,
    const float* __restrict__ W_hh, const float* __restrict__ b_ih,
    const float* __restrict__ b_hh, const float* __restrict__ W_out,
    const float* __restrict__ b_out, float* __restrict__ out,
    unsigned short* __restrict__ hbuf,   // 2 slots * 256KB, member-major
    int* __restrict__ flagsML,           // 16*16*16 ints, MALL copy (poison<0)
    int* __restrict__ flagsL2,           // 16*16*16 ints, L2 copy   (poison<0)
    int* __restrict__ xcd_ids,           // 256 ints (poison < 0)
    int* __restrict__ vflag)             // 16*16 ints (unused)
{
  const int tid  = threadIdx.x;
  const int bid  = blockIdx.x;
  const int wv   = tid >> 6;     // wave id = col-stripe 0..3 (8 cols each)
  const int lane = tid & 63;
  const int n16  = lane & 15;
  const int q    = lane >> 4;
  const int j7   = n16 & 7;
  const int hi   = n16 >> 3;     // 0: holds gates i,g ; 1: holds gates f,o

  __shared__ unsigned short h_lds[NMEM * LMEMU];  // 18KB member-major h tile
  __shared__ int xid_lds[NBLK];                   // 1KB gathered XCC ids

  // ---- publish my XCC id (device scope)
  unsigned xcc;
  asm volatile("s_getreg_b32 %0, hwreg(HW_REG_XCC_ID)" : "=s"(xcc));
  xcc &= 0xfu;
  if (tid == 0) {
    __hip_atomic_store(&xcd_ids[bid], (int)xcc, __ATOMIC_RELAXED,
                       __HIP_MEMORY_SCOPE_AGENT);
  }
  // ---- gather ALL 256 ids (thread tid spins on block tid's id).
  {
    const int* xp = &xcd_ids[tid];
    int v;
    do {
      v = __hip_atomic_load(xp, __ATOMIC_RELAXED, __HIP_MEMORY_SCOPE_AGENT);
    } while (v < 0);
    xid_lds[tid] = v & 15;
  }
  __syncthreads();

  // ---- role decision (per-thread, uniform inputs -> uniform outputs).
  unsigned long long pack = 0;
  bool bad = false;
  int myrank = 0;
  for (int b = 0; b < NBLK; ++b) {
    const int x = xid_lds[b];
    if (x < 8) pack += 1ull << (x * 8); else bad = true;
    if (b < bid && x == (int)xcc) ++myrank;
  }
  const bool remap = !bad && (pack == 0x2020202020202020ull);
  int bt, ht, fastI;
  if (remap) {
    bt = (int)xcc * 2 + (myrank >> 4);   // chain: 2 per XCD
    ht = myrank & 15;                    // member within chain
    fastI = 1;                           // same-XCD guaranteed
  } else {
    bt = bid & 15;                       // identity roles (R18)
    ht = bid >> 4;
    bool same = true;
    #pragma unroll
    for (int m = 0; m < 16; ++m)
      same = same && (xid_lds[bt + 16 * m] == (int)xcc);
    fastI = same ? 1 : 0;
  }
  const bool fast = fastI != 0;

  const int mycol = ht * HB + wv * 8 + j7;   // global hidden col

  // ---- per-thread W_ih slice + combined bias, all 4 gates of my col
  float wih[4][INDIM], bias[4];
  #pragma unroll
  for (int g = 0; g < 4; ++g) {
    const int r = g * HID + mycol;
    #pragma unroll
    for (int i = 0; i < INDIM; ++i) wih[g][i] = W_ih[r * INDIM + i];
    bias[g] = b_ih[r] + b_hh[r];
  }

  // ---- W_hh bf16 MFMA B-fragments, wave-local gate mapping:
  //   N-slot s = nt*16+n16 -> W_hh row (s>>3)*HID + ht*32 + wv*8 + (s&7)
  //   K-block kb rotated: wfrag[i][nt] <-> kb=(wv*4+i)&15
  short8 wfrag[16][2];
  {
    #pragma unroll
    for (int i = 0; i < 16; ++i) {
      const int kb = (wv * 4 + i) & 15;
      #pragma unroll
      for (int nt = 0; nt < 2; ++nt) {
        const int s = nt * 16 + n16;
        const int row = (s >> 3) * HID + ht * HB + wv * 8 + (s & 7);
        const float* p = W_hh + (size_t)row * HID + kb * 32 + q * 8;
        short8 f;
        #pragma unroll
        for (int j = 0; j < 8; ++j) f[j] = (short)f2bf_rne(p[j]);
        wfrag[i][nt] = f;
      }
    }
  }
  __syncthreads();

  // this thread's two batch rows (within chain): row0, row0+1
  const int row0 = q * 4 + 2 * hi;
  const float* sp0 = strokes + (size_t)(bt * MB + row0) * SEQ * INDIM;
  const float* sp1 = sp0 + (size_t)SEQ * INDIM;

  const int j0m = wv * 4;             // this wave's first member (staging)

  // loop-invariant poll addresses (lanes 0..15: one input flag each)
  const int fi_poll = (bt * 16 + (j0m + (lane >> 2))) * 16 + (lane & 3) * 4;
  const int* fpL = &flagsL2[fi_poll];
  const int* fpM = &flagsML[fi_poll];

  // strokes for t=0, prefetched; loop bottom prefetches t+1
  float sA[INDIM], sB[INDIM];
  #pragma unroll
  for (int i = 0; i < INDIM; ++i) {
    sA[i] = sp0[i];
    sB[i] = sp1[i];
  }

  float c0 = 0.f, c1 = 0.f;

  for (int t = 0; t < SEQ; ++t) {
    unsigned short* hprev = hbuf + (((t & 1) ^ 1) ? (SLOT_BYTES / 2) : 0);
    unsigned short* hcur  = hbuf + ((t & 1) ? (SLOT_BYTES / 2) : 0);

    f32x4 acc[2][2] = {};   // [ntile][parity]
    if (t > 0) {
      // ---- poll 4 members x 4 wave-flags (lanes 0..15): hybrid probe,
      // L2-only iterations with MALL dual-probe backstop every 8th.
      if (lane < 16) {
        if (fast) {
          int v;
          int it = 0;
          do {
            int v1, v2;
            if ((it & 7) == 7) {
              asm volatile("global_load_dword %0, %2, off sc0\n\t"
                           "global_load_dword %1, %3, off sc0 sc1\n\t"
                           "s_waitcnt vmcnt(0)"
                           : "=v"(v1), "=v"(v2)
                           : "v"(fpL), "v"(fpM)
                           : "memory");
            } else {
              asm volatile("global_load_dword %0, %1, off sc0\n\t"
                           "s_waitcnt vmcnt(0)"
                           : "=v"(v1) : "v"(fpL) : "memory");
              v2 = v1;
            }
            ++it;
            v = v1 > v2 ? v1 : v2;
          } while (v < t);
        } else {
          while (__hip_atomic_load(fpM, __ATOMIC_RELAXED,
                                   __HIP_MEMORY_SCOPE_AGENT) < t) { }
        }
      }
      // ---- stage this wave's 4 members (4 x 1KB) into LDS
      const char* base = reinterpret_cast<const char*>(hprev) + bt * 16384
                       + j0m * 1024;
      u32x4 tmp[4];
      if (fast) {
        #pragma unroll
        for (int i = 0; i < 4; ++i)
          asm volatile("global_load_dwordx4 %0, %1, off sc0"
                       : "=v"(tmp[i])
                       : "v"(base + (size_t)(i * 64 + lane) * 16) : "memory");
      } else {
        #pragma unroll
        for (int i = 0; i < 4; ++i)
          asm volatile("global_load_dwordx4 %0, %1, off sc0 sc1"
                       : "=v"(tmp[i])
                       : "v"(base + (size_t)(i * 64 + lane) * 16) : "memory");
      }
      asm volatile("s_waitcnt vmcnt(0)" ::: "memory");
      #pragma unroll
      for (int i = 0; i < 4; ++i) {
        const int idx = i * 64 + lane;     // 16B chunk index in wave's 4KB
        const int m   = j0m + (idx >> 6);  // member (64 chunks each)
        const int c   = idx & 63;          // chunk in member
        *reinterpret_cast<u32x4*>(
            &h_lds[m * LMEMU + (c >> 2) * LROWU + (c & 3) * 8]) = tmp[i];
      }

      // ---- early MFMA: the 4 kb (== members) this wave itself staged
      #pragma unroll
      for (int i = 0; i < 4; ++i) {
        const int kb = wv * 4 + i;         // own member, <16
        const short8 a = *reinterpret_cast<const short8*>(
            &h_lds[kb * LMEMU + n16 * LROWU + q * 8]);
        #pragma unroll
        for (int nt = 0; nt < 2; ++nt)
          acc[nt][i & 1] = __builtin_amdgcn_mfma_f32_16x16x32_bf16(
              a, wfrag[i][nt], acc[nt][i & 1], 0, 0, 0);
      }
      __syncthreads();   // sync#1 (the ONLY per-step barrier)
      #pragma unroll
      for (int i = 4; i < 16; ++i) {
        const int kb = (wv * 4 + i) & 15;
        const short8 a = *reinterpret_cast<const short8*>(
            &h_lds[kb * LMEMU + n16 * LROWU + q * 8]);
        #pragma unroll
        for (int nt = 0; nt < 2; ++nt)
          acc[nt][i & 1] = __builtin_amdgcn_mfma_f32_16x16x32_bf16(
              a, wfrag[i][nt], acc[nt][i & 1], 0, 0, 0);
      }
    }

    // ---- wave-local activation. C-layout: col=slot n16, row=q*4+r.
    // Lane (hi=0) holds gates {i,g}, partner lane^8 holds {f,o};
    // exchange per cell row via shfl_xor(8). No LDS, no barrier.
    const f32x4 S0 = acc[0][0] + acc[0][1];   // slot nt=0 -> gate hi
    const f32x4 S1 = acc[1][0] + acc[1][1];   // slot nt=1 -> gate hi+2
    float hv0 = 0.f, hv1 = 0.f;
    #pragma unroll
    for (int e = 0; e < 2; ++e) {
      float mine0 = hi ? S0[2 + e] : S0[e];
      float send0 = hi ? S0[e]     : S0[2 + e];
      float mine1 = hi ? S1[2 + e] : S1[e];
      float send1 = hi ? S1[e]     : S1[2 + e];
      float got0 = __shfl_xor(send0, 8);
      float got1 = __shfl_xor(send1, 8);
      float pi = hi ? got0  : mine0;
      float pf = hi ? mine0 : got0;
      float pg = hi ? got1  : mine1;
      float po = hi ? mine1 : got1;
      const float* s = e ? sB : sA;
      pi += bias[0] + s[0]*wih[0][0] + s[1]*wih[0][1] + s[2]*wih[0][2]
                    + s[3]*wih[0][3] + s[4]*wih[0][4];
      pf += bias[1] + s[0]*wih[1][0] + s[1]*wih[1][1] + s[2]*wih[1][2]
                    + s[3]*wih[1][3] + s[4]*wih[1][4];
      pg += bias[2] + s[0]*wih[2][0] + s[1]*wih[2][1] + s[2]*wih[2][2]
                    + s[3]*wih[2][3] + s[4]*wih[2][4];
      po += bias[3] + s[0]*wih[3][0] + s[1]*wih[3][1] + s[2]*wih[3][2]
                    + s[3]*wih[3][3] + s[4]*wih[3][4];
      float ig = sigmoidf_fast(pi);
      float fg = sigmoidf_fast(pf);
      float gg = tanhf_fast(pg);
      float og = sigmoidf_fast(po);
      float& c = e ? c1 : c0;
      c = fg * c + ig * gg;
      float hv = og * tanhf_fast(c);
      if (e == 0) hv0 = hv; else hv1 = hv;
    }

    // ---- pack 2 adjacent cols into one dword via shfl_xor(1):
    // even j7 stores row row0 (cols j7,j7+1); odd j7 stores row row0+1.
    {
      float sendh = (j7 & 1) ? hv0 : hv1;
      float rh = __shfl_xor(sendh, 1);
      unsigned lo = (j7 & 1) ? (unsigned)f2bf_rne(rh)  : (unsigned)f2bf_rne(hv0);
      unsigned hh = (j7 & 1) ? (unsigned)f2bf_rne(hv1) : (unsigned)f2bf_rne(rh);
      unsigned pack2 = lo | (hh << 16);
      const int srow = row0 + (j7 & 1);
      const int colp = wv * 8 + (j7 & ~1);
      unsigned* hp = reinterpret_cast<unsigned*>(
          reinterpret_cast<char*>(hcur) + bt * 16384 + ht * 1024
          + srow * 64 + colp * 2);
      if (fast) {
        asm volatile("global_store_dword %0, %1, off sc0"
                     :: "v"(hp), "v"(pack2) : "memory");
      } else {
        __hip_atomic_store(hp, pack2, __ATOMIC_RELAXED,
                           __HIP_MEMORY_SCOPE_AGENT);
      }
    }

    // ---- per-wave publish: drain OWN wave's h stores, then flag (no sync)
    asm volatile("s_waitcnt vmcnt(0)" ::: "memory");
    const int gen = t + 1;
    if (lane == 0) {
      const int fi = (bt * 16 + ht) * 16 + wv * 4;
      if (fast) {
        asm volatile("global_store_dword %0, %1, off sc0"
                     :: "v"(&flagsL2[fi]), "v"(gen) : "memory");
      }
      __hip_atomic_store(&flagsML[fi], gen, __ATOMIC_RELAXED,
                         __HIP_MEMORY_SCOPE_AGENT);   // MALL copy
    }

    // ---- STROKE PREFETCH for t+1 (after publish: never delays the flag;
    // lands during the next poll, so the poll's vmcnt(0) sees it retired)
    {
      const int tn = (t + 1 < SEQ) ? t + 1 : t;
      #pragma unroll
      for (int i = 0; i < INDIM; ++i) {
        sA[i] = sp0[tn * INDIM + i];
        sB[i] = sp1[tn * INDIM + i];
      }
    }
  }

  // ---- final projection: member ht==0 of each chain, 16 rows
  if (ht == 0) {
    if (lane < 16) {
      if (fast) {
        int v;
        int it = 0;
        do {
          int v1, v2;
          if ((it & 3) == 3) {
            asm volatile("global_load_dword %0, %2, off sc0\n\t"
                         "global_load_dword %1, %3, off sc0 sc1\n\t"
                         "s_waitcnt vmcnt(0)"
                         : "=v"(v1), "=v"(v2)
                         : "v"(fpL), "v"(fpM)
                         : "memory");
          } else {
            asm volatile("global_load_dword %0, %1, off sc0\n\t"
                         "s_waitcnt vmcnt(0)"
                         : "=v"(v1) : "v"(fpL) : "memory");
            v2 = v1;
          }
          ++it;
          v = v1 > v2 ? v1 : v2;
        } while (v < SEQ);
      } else {
        while (__hip_atomic_load(fpM, __ATOMIC_RELAXED,
                                 __HIP_MEMORY_SCOPE_AGENT) < SEQ) { }
      }
    }
    const char* base = reinterpret_cast<const char*>(hbuf)
                     + ((SEQ - 1) & 1) * SLOT_BYTES + bt * 16384 + j0m * 1024;
    u32x4 tmp[4];
    if (fast) {
      #pragma unroll
      for (int i = 0; i < 4; ++i)
        asm volatile("global_load_dwordx4 %0, %1, off sc0"
                     : "=v"(tmp[i])
                     : "v"(base + (size_t)(i * 64 + lane) * 16) : "memory");
    } else {
      #pragma unroll
      for (int i = 0; i < 4; ++i)
        asm volatile("global_load_dwordx4 %0, %1, off sc0 sc1"
                     : "=v"(tmp[i])
                     : "v"(base + (size_t)(i * 64 + lane) * 16) : "memory");
    }
    asm volatile("s_waitcnt vmcnt(0)" ::: "memory");
    #pragma unroll
    for (int i = 0; i < 4; ++i) {
      const int idx = i * 64 + lane;
      const int m   = j0m + (idx >> 6);
      const int c   = idx & 63;
      *reinterpret_cast<u32x4*>(
          &h_lds[m * LMEMU + (c >> 2) * LROWU + (c & 3) * 8]) = tmp[i];
    }
    __syncthreads();
    if (tid < MB) {
      const int b = bt * MB + tid;
      float s = 0.f;
      for (int k = 0; k < HID; ++k) {
        s += bf2f(h_lds[(k >> 5) * LMEMU + tid * LROWU + (k & 31)]) * W_out[k];
      }
      float raw = s + b_out[0];
      float lr = raw > 0.f ? raw : 0.1f * raw;
      out[b] = 1.0f / (1.0f + __expf(-lr));
    }
  }
}

extern "C" void kernel_launch(void* const* d_in, const int* in_sizes, int n_in,
                              void* d_out, int out_size, void* d_ws, size_t ws_size,
                              hipStream_t stream) {
  const float* strokes = (const float*)d_in[0];
  const float* W_ih    = (const float*)d_in[1];
  const float* W_hh    = (const float*)d_in[2];
  const float* b_ih    = (const float*)d_in[3];
  const float* b_hh    = (const float*)d_in[4];
  const float* W_out   = (const float*)d_in[5];
  const float* b_out   = (const float*)d_in[6];
  float* out = (float*)d_out;

  char* ws = (char*)d_ws;
  unsigned short* hbuf = (unsigned short*)ws;                 // 512 KB (2 slots)
  size_t off = (size_t)2 * SLOT_BYTES;
  int* flagsML = (int*)(ws + off);  off += 16384;             // 16 KB
  int* flagsL2 = (int*)(ws + off);  off += 16384;             // 16 KB
  int* xcd_ids = (int*)(ws + off);  off += 2048;              // 2 KB
  int* vflag   = (int*)(ws + off);                            // 1 KB (unused)

  lstm_persist<<<NBLK, 256, 0, stream>>>(strokes, W_ih, W_hh, b_ih, b_hh,
                                         W_out, b_out, out, hbuf,
                                         flagsML, flagsL2, xcd_ids, vflag);
}

// Round 10
// 688.091 us; speedup vs baseline: 1.2716x; 1.2001x over previous
//
#include <hip/hip_runtime.h>

#define BATCH 256
#define SEQ   250
#define HID   512
#define INDIM 5

#define NBLK  256
#define NCH   16   // independent batch chains
#define MB    16   // batch rows per chain/block
#define HB    32   // hidden cols per block (member)
#define NMEM  16   // members per chain (HID/HB)

// member-major h buffers: slot (2) | chain bt (16) | member j (16) | 1KB
// LDS member block: 16 rows x 36 ushorts (72B: 64B data + 8B pad)
#define LROWU 36          // ushorts per LDS row
#define LMEMU 576         // ushorts per member block (16*36)
#define SLOT_BYTES (BATCH * HID * 2)   // 256KB per slot

typedef __attribute__((ext_vector_type(8))) short short8;
typedef __attribute__((ext_vector_type(4))) float f32x4;
typedef __attribute__((ext_vector_type(4))) unsigned int u32x4;

__device__ __forceinline__ float sigmoidf_fast(float x) {
  return 1.0f / (1.0f + __expf(-x));
}
__device__ __forceinline__ float tanhf_fast(float x) {
  return 2.0f / (1.0f + __expf(-2.0f * x)) - 1.0f;
}
__device__ __forceinline__ unsigned short f2bf_rne(float x) {
  union { float f; unsigned u; } v; v.f = x;
  unsigned r = v.u + 0x7fffu + ((v.u >> 16) & 1u);
  return (unsigned short)(r >> 16);
}
__device__ __forceinline__ float bf2f(unsigned short h) {
  union { unsigned u; float f; } v; v.u = ((unsigned)h) << 16;
  return v.f;
}

// R24 == R21 byte-for-byte resubmission (reproducibility test).
// R21 measured 665us; R22 (-backstop rate, +ping-pong) and R23
// (-backstop rate, stroke prefetch) BOTH regressed to ~800-815.
// Common factor: reduced MALL-backstop cadence (4th -> 8th). Hypothesis:
// un-paced L2 probes contend on the hot flag lines and delay the
// producer's flag store; the every-4th dual-probe stall is accidental
// pacing. This run decides: 665 reproduced -> pacing theory confirmed
// (next: s_sleep pacing); ~800-840 -> R21 was run-to-run luck.
// Structure: remap + R18 protocol + hybrid poll (3x L2-only probe, every
// 4th = fused dual L2+MALL backstop; cannot hang).
__global__ __launch_bounds__(256, 1) void lstm_persist(
    const float* __restrict__ strokes, const float* __restrict__ W_ih,
    const float* __restrict__ W_hh, const float* __restrict__ b_ih,
    const float* __restrict__ b_hh, const float* __restrict__ W_out,
    const float* __restrict__ b_out, float* __restrict__ out,
    unsigned short* __restrict__ hbuf,   // 2 slots * 256KB, member-major
    int* __restrict__ flagsML,           // 16*16*16 ints, MALL copy (poison<0)
    int* __restrict__ flagsL2,           // 16*16*16 ints, L2 copy   (poison<0)
    int* __restrict__ xcd_ids,           // 256 ints (poison < 0)
    int* __restrict__ vflag)             // 16*16 ints (unused)
{
  const int tid  = threadIdx.x;
  const int bid  = blockIdx.x;
  const int wv   = tid >> 6;     // wave id = col-stripe 0..3 (8 cols each)
  const int lane = tid & 63;
  const int n16  = lane & 15;
  const int q    = lane >> 4;
  const int j7   = n16 & 7;
  const int hi   = n16 >> 3;     // 0: holds gates i,g ; 1: holds gates f,o

  __shared__ unsigned short h_lds[NMEM * LMEMU];  // 18KB member-major h tile
  __shared__ int xid_lds[NBLK];                   // 1KB gathered XCC ids

  // ---- publish my XCC id (device scope)
  unsigned xcc;
  asm volatile("s_getreg_b32 %0, hwreg(HW_REG_XCC_ID)" : "=s"(xcc));
  xcc &= 0xfu;
  if (tid == 0) {
    __hip_atomic_store(&xcd_ids[bid], (int)xcc, __ATOMIC_RELAXED,
                       __HIP_MEMORY_SCOPE_AGENT);
  }
  // ---- gather ALL 256 ids (thread tid spins on block tid's id).
  {
    const int* xp = &xcd_ids[tid];
    int v;
    do {
      v = __hip_atomic_load(xp, __ATOMIC_RELAXED, __HIP_MEMORY_SCOPE_AGENT);
    } while (v < 0);
    xid_lds[tid] = v & 15;
  }
  __syncthreads();

  // ---- role decision (per-thread, uniform inputs -> uniform outputs).
  unsigned long long pack = 0;
  bool bad = false;
  int myrank = 0;
  for (int b = 0; b < NBLK; ++b) {
    const int x = xid_lds[b];
    if (x < 8) pack += 1ull << (x * 8); else bad = true;
    if (b < bid && x == (int)xcc) ++myrank;
  }
  const bool remap = !bad && (pack == 0x2020202020202020ull);
  int bt, ht, fastI;
  if (remap) {
    bt = (int)xcc * 2 + (myrank >> 4);   // chain: 2 per XCD
    ht = myrank & 15;                    // member within chain
    fastI = 1;                           // same-XCD guaranteed
  } else {
    bt = bid & 15;                       // identity roles (R18)
    ht = bid >> 4;
    bool same = true;
    #pragma unroll
    for (int m = 0; m < 16; ++m)
      same = same && (xid_lds[bt + 16 * m] == (int)xcc);
    fastI = same ? 1 : 0;
  }
  const bool fast = fastI != 0;

  const int mycol = ht * HB + wv * 8 + j7;   // global hidden col

  // ---- per-thread W_ih slice + combined bias, all 4 gates of my col
  float wih[4][INDIM], bias[4];
  #pragma unroll
  for (int g = 0; g < 4; ++g) {
    const int r = g * HID + mycol;
    #pragma unroll
    for (int i = 0; i < INDIM; ++i) wih[g][i] = W_ih[r * INDIM + i];
    bias[g] = b_ih[r] + b_hh[r];
  }

  // ---- W_hh bf16 MFMA B-fragments, wave-local gate mapping:
  //   N-slot s = nt*16+n16 -> W_hh row (s>>3)*HID + ht*32 + wv*8 + (s&7)
  //   K-block kb rotated: wfrag[i][nt] <-> kb=(wv*4+i)&15
  short8 wfrag[16][2];
  {
    #pragma unroll
    for (int i = 0; i < 16; ++i) {
      const int kb = (wv * 4 + i) & 15;
      #pragma unroll
      for (int nt = 0; nt < 2; ++nt) {
        const int s = nt * 16 + n16;
        const int row = (s >> 3) * HID + ht * HB + wv * 8 + (s & 7);
        const float* p = W_hh + (size_t)row * HID + kb * 32 + q * 8;
        short8 f;
        #pragma unroll
        for (int j = 0; j < 8; ++j) f[j] = (short)f2bf_rne(p[j]);
        wfrag[i][nt] = f;
      }
    }
  }
  __syncthreads();

  // this thread's two batch rows (within chain): row0, row0+1
  const int row0 = q * 4 + 2 * hi;
  const float* sp0 = strokes + (size_t)(bt * MB + row0) * SEQ * INDIM;
  const float* sp1 = sp0 + (size_t)SEQ * INDIM;

  const int j0m = wv * 4;             // this wave's first member (staging)
  float c0 = 0.f, c1 = 0.f;

  for (int t = 0; t < SEQ; ++t) {
    unsigned short* hprev = hbuf + (((t & 1) ^ 1) ? (SLOT_BYTES / 2) : 0);
    unsigned short* hcur  = hbuf + ((t & 1) ? (SLOT_BYTES / 2) : 0);

    // strokes for this step (2 rows) - issued early, drained by poll/stage
    float sA[INDIM], sB[INDIM];
    #pragma unroll
    for (int i = 0; i < INDIM; ++i) {
      sA[i] = sp0[t * INDIM + i];
      sB[i] = sp1[t * INDIM + i];
    }

    f32x4 acc[2][2] = {};   // [ntile][parity]
    if (t > 0) {
      // ---- poll 4 members x 4 wave-flags (lanes 0..15): HYBRID probe.
      // 3x cheap L2-only (sc0) iterations, then 1 dual-probe (L2+MALL)
      // backstop; repeats forever -> cannot hang even if L2 visibility
      // stalls. Common case: flag already in L2 -> one ~250cy iteration.
      if (lane < 16) {
        const int fi = (bt * 16 + (j0m + (lane >> 2))) * 16 + (lane & 3) * 4;
        const int* fpL = &flagsL2[fi];
        const int* fpM = &flagsML[fi];
        if (fast) {
          int v;
          int it = 0;
          do {
            int v1, v2;
            if ((it & 3) == 3) {
              asm volatile("global_load_dword %0, %2, off sc0\n\t"
                           "global_load_dword %1, %3, off sc0 sc1\n\t"
                           "s_waitcnt vmcnt(0)"
                           : "=v"(v1), "=v"(v2)
                           : "v"(fpL), "v"(fpM)
                           : "memory");
            } else {
              asm volatile("global_load_dword %0, %1, off sc0\n\t"
                           "s_waitcnt vmcnt(0)"
                           : "=v"(v1) : "v"(fpL) : "memory");
              v2 = v1;
            }
            ++it;
            v = v1 > v2 ? v1 : v2;
          } while (v < t);
        } else {
          while (__hip_atomic_load(fpM, __ATOMIC_RELAXED,
                                   __HIP_MEMORY_SCOPE_AGENT) < t) { }
        }
      }
      // ---- stage this wave's 4 members (4 x 1KB) into LDS
      const char* base = reinterpret_cast<const char*>(hprev) + bt * 16384
                       + j0m * 1024;
      u32x4 tmp[4];
      if (fast) {
        #pragma unroll
        for (int i = 0; i < 4; ++i)
          asm volatile("global_load_dwordx4 %0, %1, off sc0"
                       : "=v"(tmp[i])
                       : "v"(base + (size_t)(i * 64 + lane) * 16) : "memory");
      } else {
        #pragma unroll
        for (int i = 0; i < 4; ++i)
          asm volatile("global_load_dwordx4 %0, %1, off sc0 sc1"
                       : "=v"(tmp[i])
                       : "v"(base + (size_t)(i * 64 + lane) * 16) : "memory");
      }
      asm volatile("s_waitcnt vmcnt(0)" ::: "memory");
      #pragma unroll
      for (int i = 0; i < 4; ++i) {
        const int idx = i * 64 + lane;     // 16B chunk index in wave's 4KB
        const int m   = j0m + (idx >> 6);  // member (64 chunks each)
        const int c   = idx & 63;          // chunk in member
        *reinterpret_cast<u32x4*>(
            &h_lds[m * LMEMU + (c >> 2) * LROWU + (c & 3) * 8]) = tmp[i];
      }

      // ---- early MFMA: the 4 kb (== members) this wave itself staged
      #pragma unroll
      for (int i = 0; i < 4; ++i) {
        const int kb = wv * 4 + i;         // own member, <16
        const short8 a = *reinterpret_cast<const short8*>(
            &h_lds[kb * LMEMU + n16 * LROWU + q * 8]);
        #pragma unroll
        for (int nt = 0; nt < 2; ++nt)
          acc[nt][i & 1] = __builtin_amdgcn_mfma_f32_16x16x32_bf16(
              a, wfrag[i][nt], acc[nt][i & 1], 0, 0, 0);
      }
      __syncthreads();   // sync#1 (the ONLY per-step barrier)
      #pragma unroll
      for (int i = 4; i < 16; ++i) {
        const int kb = (wv * 4 + i) & 15;
        const short8 a = *reinterpret_cast<const short8*>(
            &h_lds[kb * LMEMU + n16 * LROWU + q * 8]);
        #pragma unroll
        for (int nt = 0; nt < 2; ++nt)
          acc[nt][i & 1] = __builtin_amdgcn_mfma_f32_16x16x32_bf16(
              a, wfrag[i][nt], acc[nt][i & 1], 0, 0, 0);
      }
    }

    // ---- wave-local activation. C-layout: col=slot n16, row=q*4+r.
    // Lane (hi=0) holds gates {i,g}, partner lane^8 holds {f,o};
    // exchange per cell row via shfl_xor(8). No LDS, no barrier.
    const f32x4 S0 = acc[0][0] + acc[0][1];   // slot nt=0 -> gate hi
    const f32x4 S1 = acc[1][0] + acc[1][1];   // slot nt=1 -> gate hi+2
    float hv0 = 0.f, hv1 = 0.f;
    #pragma unroll
    for (int e = 0; e < 2; ++e) {
      float mine0 = hi ? S0[2 + e] : S0[e];
      float send0 = hi ? S0[e]     : S0[2 + e];
      float mine1 = hi ? S1[2 + e] : S1[e];
      float send1 = hi ? S1[e]     : S1[2 + e];
      float got0 = __shfl_xor(send0, 8);
      float got1 = __shfl_xor(send1, 8);
      float pi = hi ? got0  : mine0;
      float pf = hi ? mine0 : got0;
      float pg = hi ? got1  : mine1;
      float po = hi ? mine1 : got1;
      const float* s = e ? sB : sA;
      pi += bias[0] + s[0]*wih[0][0] + s[1]*wih[0][1] + s[2]*wih[0][2]
                    + s[3]*wih[0][3] + s[4]*wih[0][4];
      pf += bias[1] + s[0]*wih[1][0] + s[1]*wih[1][1] + s[2]*wih[1][2]
                    + s[3]*wih[1][3] + s[4]*wih[1][4];
      pg += bias[2] + s[0]*wih[2][0] + s[1]*wih[2][1] + s[2]*wih[2][2]
                    + s[3]*wih[2][3] + s[4]*wih[2][4];
      po += bias[3] + s[0]*wih[3][0] + s[1]*wih[3][1] + s[2]*wih[3][2]
                    + s[3]*wih[3][3] + s[4]*wih[3][4];
      float ig = sigmoidf_fast(pi);
      float fg = sigmoidf_fast(pf);
      float gg = tanhf_fast(pg);
      float og = sigmoidf_fast(po);
      float& c = e ? c1 : c0;
      c = fg * c + ig * gg;
      float hv = og * tanhf_fast(c);
      if (e == 0) hv0 = hv; else hv1 = hv;
    }

    // ---- pack 2 adjacent cols into one dword via shfl_xor(1):
    // even j7 stores row row0 (cols j7,j7+1); odd j7 stores row row0+1.
    {
      float sendh = (j7 & 1) ? hv0 : hv1;
      float rh = __shfl_xor(sendh, 1);
      unsigned lo = (j7 & 1) ? (unsigned)f2bf_rne(rh)  : (unsigned)f2bf_rne(hv0);
      unsigned hh = (j7 & 1) ? (unsigned)f2bf_rne(hv1) : (unsigned)f2bf_rne(rh);
      unsigned pack2 = lo | (hh << 16);
      const int srow = row0 + (j7 & 1);
      const int colp = wv * 8 + (j7 & ~1);
      unsigned* hp = reinterpret_cast<unsigned*>(
          reinterpret_cast<char*>(hcur) + bt * 16384 + ht * 1024
          + srow * 64 + colp * 2);
      if (fast) {
        asm volatile("global_store_dword %0, %1, off sc0"
                     :: "v"(hp), "v"(pack2) : "memory");
      } else {
        __hip_atomic_store(hp, pack2, __ATOMIC_RELAXED,
                           __HIP_MEMORY_SCOPE_AGENT);
      }
    }

    // ---- per-wave publish: drain OWN wave's h stores, then flag (no sync)
    asm volatile("s_waitcnt vmcnt(0)" ::: "memory");
    const int gen = t + 1;
    if (lane == 0) {
      const int fi = (bt * 16 + ht) * 16 + wv * 4;
      if (fast) {
        asm volatile("global_store_dword %0, %1, off sc0"
                     :: "v"(&flagsL2[fi]), "v"(gen) : "memory");
      }
      __hip_atomic_store(&flagsML[fi], gen, __ATOMIC_RELAXED,
                         __HIP_MEMORY_SCOPE_AGENT);   // MALL copy
    }
  }

  // ---- final projection: member ht==0 of each chain, 16 rows
  if (ht == 0) {
    if (lane < 16) {
      const int fi = (bt * 16 + (j0m + (lane >> 2))) * 16 + (lane & 3) * 4;
      const int* fpL = &flagsL2[fi];
      const int* fpM = &flagsML[fi];
      if (fast) {
        int v;
        int it = 0;
        do {
          int v1, v2;
          if ((it & 3) == 3) {
            asm volatile("global_load_dword %0, %2, off sc0\n\t"
                         "global_load_dword %1, %3, off sc0 sc1\n\t"
                         "s_waitcnt vmcnt(0)"
                         : "=v"(v1), "=v"(v2)
                         : "v"(fpL), "v"(fpM)
                         : "memory");
          } else {
            asm volatile("global_load_dword %0, %1, off sc0\n\t"
                         "s_waitcnt vmcnt(0)"
                         : "=v"(v1) : "v"(fpL) : "memory");
            v2 = v1;
          }
          ++it;
          v = v1 > v2 ? v1 : v2;
        } while (v < SEQ);
      } else {
        while (__hip_atomic_load(fpM, __ATOMIC_RELAXED,
                                 __HIP_MEMORY_SCOPE_AGENT) < SEQ) { }
      }
    }
    const char* base = reinterpret_cast<const char*>(hbuf)
                     + ((SEQ - 1) & 1) * SLOT_BYTES + bt * 16384 + j0m * 1024;
    u32x4 tmp[4];
    if (fast) {
      #pragma unroll
      for (int i = 0; i < 4; ++i)
        asm volatile("global_load_dwordx4 %0, %1, off sc0"
                     : "=v"(tmp[i])
                     : "v"(base + (size_t)(i * 64 + lane) * 16) : "memory");
    } else {
      #pragma unroll
      for (int i = 0; i < 4; ++i)
        asm volatile("global_load_dwordx4 %0, %1, off sc0 sc1"
                     : "=v"(tmp[i])
                     : "v"(base + (size_t)(i * 64 + lane) * 16) : "memory");
    }
    asm volatile("s_waitcnt vmcnt(0)" ::: "memory");
    #pragma unroll
    for (int i = 0; i < 4; ++i) {
      const int idx = i * 64 + lane;
      const int m   = j0m + (idx >> 6);
      const int c   = idx & 63;
      *reinterpret_cast<u32x4*>(
          &h_lds[m * LMEMU + (c >> 2) * LROWU + (c & 3) * 8]) = tmp[i];
    }
    __syncthreads();
    if (tid < MB) {
      const int b = bt * MB + tid;
      float s = 0.f;
      for (int k = 0; k < HID; ++k) {
        s += bf2f(h_lds[(k >> 5) * LMEMU + tid * LROWU + (k & 31)]) * W_out[k];
      }
      float raw = s + b_out[0];
      float lr = raw > 0.f ? raw : 0.1f * raw;
      out[b] = 1.0f / (1.0f + __expf(-lr));
    }
  }
}

extern "C" void kernel_launch(void* const* d_in, const int* in_sizes, int n_in,
                              void* d_out, int out_size, void* d_ws, size_t ws_size,
                              hipStream_t stream) {
  const float* strokes = (const float*)d_in[0];
  const float* W_ih    = (const float*)d_in[1];
  const float* W_hh    = (const float*)d_in[2];
  const float* b_ih    = (const float*)d_in[3];
  const float* b_hh    = (const float*)d_in[4];
  const float* W_out   = (const float*)d_in[5];
  const float* b_out   = (const float*)d_in[6];
  float* out = (float*)d_out;

  char* ws = (char*)d_ws;
  unsigned short* hbuf = (unsigned short*)ws;                 // 512 KB (2 slots)
  size_t off = (size_t)2 * SLOT_BYTES;
  int* flagsML = (int*)(ws + off);  off += 16384;             // 16 KB
  int* flagsL2 = (int*)(ws + off);  off += 16384;             // 16 KB
  int* xcd_ids = (int*)(ws + off);  off += 2048;              // 2 KB
  int* vflag   = (int*)(ws + off);                            // 1 KB (unused)

  lstm_persist<<<NBLK, 256, 0, stream>>>(strokes, W_ih, W_hh, b_ih, b_hh,
                                         W_out, b_out, out, hbuf,
                                         flagsML, flagsL2, xcd_ids, vflag);
}